// Round 14
// baseline (276.589 us; speedup 1.0000x reference)
//
#include <hip/hip_runtime.h>

#define BB 4
#define NN 256
#define DD 256
#define HH 256
#define NEGV -1.0e9f

typedef _Float16 half8 __attribute__((ext_vector_type(8)));
typedef __fp16   fp16x2 __attribute__((ext_vector_type(2)));
typedef __fp16   fp16x4 __attribute__((ext_vector_type(4)));
typedef float floatx4 __attribute__((ext_vector_type(4)));

// ---------------- prep: Wc/Wd -> f16 frag-contiguous (diff|prod split); Xh; S/T
// Wst layout: [ks 0..15][hgrp 0..15][q 0..3][cc 0..15][e 0..7] halves.
// NEW k-map: frag element e<4 -> Wc[dbase+e][h] (diff), e>=4 -> Wd[dbase+e-4][h]
// (prod), dbase = ks*16+q*4 — matches packed A-gen [diff0..3|prod0..3].
// Xh layout: [b][dq 0..63][j 0..255][dd 0..3] f16 — one half4 = the 4 d's of a
// frag element (d = dq*4+dd); lane loads are j-contiguous 8 B.
__global__ __launch_bounds__(256) void prep_kernel(const float* __restrict__ X,
                                                   const float* __restrict__ W1,
                                                   float* __restrict__ S,
                                                   float* __restrict__ T,
                                                   _Float16* __restrict__ Wst,
                                                   _Float16* __restrict__ Xh) {
  const int g = blockIdx.x;    // d = 0..255
  const int h = threadIdx.x;   // 0..255

  {
    const float wcv = W1[(size_t)(2 * DD + g) * HH + h];
    const float wdv = W1[(size_t)(3 * DD + g) * HH + h];
    const int ks  = g >> 4;
    const int q   = (g >> 2) & 3;
    const int dd3 = g & 3;
    const int hgrp = h >> 4;
    const int ccw  = h & 15;
    _Float16* p = Wst + ((size_t)((ks * 16 + hgrp) * 4 + q) * 16 + ccw) * 8;
    p[dd3]     = (_Float16)wcv;   // diff weight
    p[4 + dd3] = (_Float16)wdv;   // prod weight
  }

  const int row0 = g * 4;
  __shared__ float xr[4][DD];
#pragma unroll
  for (int r = 0; r < 4; ++r) xr[r][h] = X[(size_t)(row0 + r) * DD + h];
  __syncthreads();

  {
    const int bb = row0 >> 8;
    const int j0 = row0 & 255;
    // Xh[bb][h>>2][j0+r][h&3]
    _Float16* xt = Xh + (((size_t)bb * 64 + (h >> 2)) * 256 + j0) * 4 + (h & 3);
    xt[0]  = (_Float16)xr[0][h];
    xt[4]  = (_Float16)xr[1][h];
    xt[8]  = (_Float16)xr[2][h];
    xt[12] = (_Float16)xr[3][h];
  }

  const float* __restrict__ Wa = W1;
  const float* __restrict__ Wb = W1 + (size_t)DD * HH;
  float sa0 = 0.f, sa1 = 0.f, sa2 = 0.f, sa3 = 0.f;
  float sb0 = 0.f, sb1 = 0.f, sb2 = 0.f, sb3 = 0.f;
#pragma unroll 4
  for (int d = 0; d < DD; ++d) {
    const float wa = Wa[(size_t)d * HH + h];
    const float wb = Wb[(size_t)d * HH + h];
    sa0 = fmaf(xr[0][d], wa, sa0);  sb0 = fmaf(xr[0][d], wb, sb0);
    sa1 = fmaf(xr[1][d], wa, sa1);  sb1 = fmaf(xr[1][d], wb, sb1);
    sa2 = fmaf(xr[2][d], wa, sa2);  sb2 = fmaf(xr[2][d], wb, sb2);
    sa3 = fmaf(xr[3][d], wa, sa3);  sb3 = fmaf(xr[3][d], wb, sb3);
  }
  S[(size_t)(row0 + 0) * HH + h] = sa0;  T[(size_t)(row0 + 0) * HH + h] = sb0;
  S[(size_t)(row0 + 1) * HH + h] = sa1;  T[(size_t)(row0 + 1) * HH + h] = sb1;
  S[(size_t)(row0 + 2) * HH + h] = sa2;  T[(size_t)(row0 + 2) * HH + h] = sb2;
  S[(size_t)(row0 + 3) * HH + h] = sa3;  T[(size_t)(row0 + 3) * HH + h] = sb3;
}

// Packed A-frag: [ |xi-xj| (4 halves) | xi*xj (4 halves) ] — 6 VALU instrs
// (2 v_pk_add w/ neg, 2 v_and abs-mask, 2 v_pk_mul) vs 12 for the fp32 path.
__device__ __forceinline__ half8 make_afrag_pk(fp16x4 xi, fp16x4 xj) {
  fp16x4 d = xi - xj;
  fp16x4 p = xi * xj;
  const uint2 du = __builtin_bit_cast(uint2, d);
  const uint2 pu = __builtin_bit_cast(uint2, p);
  uint4 u;
  u.x = du.x & 0x7FFF7FFFu;
  u.y = du.y & 0x7FFF7FFFu;
  u.z = pu.x;
  u.w = pu.y;
  return __builtin_bit_cast(half8, u);
}

#define MFMA16(af, bf, acc) acc = __builtin_amdgcn_mfma_f32_16x16x32_f16(af, bf, acc, 0, 0, 0)

// ---------------- score: one block per (b,i) x 64-j quarter --------------------
// 4096 blocks x 256 thr = 4 waves, hg = wid (h-group of 64); all waves share the
// block's 4 j-tiles. Wave tile 4j x 4h, acc 64 VGPR. Barrier-free K-loop (R13).
// A-gen: packed f16 (6 VALU/frag) from f16 Xh (8 B loads) — halves R13's VALU.
__global__ __launch_bounds__(256) void score_mfma(
    const float* __restrict__ X,  const float* __restrict__ b1,
    const float* __restrict__ W2, const float* __restrict__ b2,
    const float* __restrict__ S,  const float* __restrict__ T,
    const _Float16* __restrict__ Wst, const _Float16* __restrict__ Xh,
    float* __restrict__ Sc) {

  const int blk   = blockIdx.x;
  const int bi    = blk >> 2;       // b*256 + i
  const int jbase = (blk & 3) * 64;
  const int b     = bi >> 8;
  const int i     = bi & 255;
  const int t     = threadIdx.x;
  const int lane  = t & 63;
  const int hg    = t >> 6;         // 0..3
  const int q     = lane >> 4;
  const int cc    = lane & 15;

  __shared__ __align__(8) _Float16 xi_h[DD];
  __shared__ float pre_s[HH];
  __shared__ float w2_s[HH];
  __shared__ float sc_s[4][64];

  xi_h[t]  = (_Float16)X[(size_t)bi * DD + t];
  pre_s[t] = S[(size_t)bi * HH + t] + b1[t];
  w2_s[t]  = W2[t];
  __syncthreads();                    // the only pre-epilogue barrier

  const float* __restrict__ Tb = T + (size_t)b * NN * HH;

  // A source: Xh quad (ks*4+q), j = jbase + jj*16 + cc  (halves; jj adds 64)
  const _Float16* __restrict__ xhb = Xh + (size_t)b * 65536;
  const int xj0 = (jbase + cc) * 4;

  // B source: byte addr Wst + ks*16384 + hg*4096 + lane*16 (+1024 per hh)
  const char* __restrict__ bsrc = (const char*)Wst + hg * 4096 + (size_t)lane * 16;

  floatx4 a00 = (floatx4)0.f, a01 = (floatx4)0.f, a02 = (floatx4)0.f, a03 = (floatx4)0.f;
  floatx4 a10 = (floatx4)0.f, a11 = (floatx4)0.f, a12 = (floatx4)0.f, a13 = (floatx4)0.f;
  floatx4 a20 = (floatx4)0.f, a21 = (floatx4)0.f, a22 = (floatx4)0.f, a23 = (floatx4)0.f;
  floatx4 a30 = (floatx4)0.f, a31 = (floatx4)0.f, a32 = (floatx4)0.f, a33 = (floatx4)0.f;

#pragma unroll 2
  for (int ks = 0; ks < 16; ++ks) {
    const fp16x4 xiv = *(const fp16x4*)&xi_h[(ks * 4 + q) * 4];
    const char* bk = bsrc + ks * 16384;
    const half8 bf0 = *(const half8*)(bk);
    const half8 bf1 = *(const half8*)(bk + 1024);
    const half8 bf2 = *(const half8*)(bk + 2048);
    const half8 bf3 = *(const half8*)(bk + 3072);
    const _Float16* __restrict__ xrow = xhb + (size_t)(ks * 4 + q) * 1024 + xj0;
    {
      const fp16x4 xj = *(const fp16x4*)(xrow);
      const half8 af = make_afrag_pk(xiv, xj);
      MFMA16(af, bf0, a00); MFMA16(af, bf1, a01); MFMA16(af, bf2, a02); MFMA16(af, bf3, a03);
    }
    {
      const fp16x4 xj = *(const fp16x4*)(xrow + 64);
      const half8 af = make_afrag_pk(xiv, xj);
      MFMA16(af, bf0, a10); MFMA16(af, bf1, a11); MFMA16(af, bf2, a12); MFMA16(af, bf3, a13);
    }
    {
      const fp16x4 xj = *(const fp16x4*)(xrow + 128);
      const half8 af = make_afrag_pk(xiv, xj);
      MFMA16(af, bf0, a20); MFMA16(af, bf1, a21); MFMA16(af, bf2, a22); MFMA16(af, bf3, a23);
    }
    {
      const fp16x4 xj = *(const fp16x4*)(xrow + 192);
      const half8 af = make_afrag_pk(xiv, xj);
      MFMA16(af, bf0, a30); MFMA16(af, bf1, a31); MFMA16(af, bf2, a32); MFMA16(af, bf3, a33);
    }
  }

  // ---- epilogue: + S_i + T_j + b1, silu, dot w2 ----
  float p00 = 0.f, p01 = 0.f, p02 = 0.f, p03 = 0.f;
  float p10 = 0.f, p11 = 0.f, p12 = 0.f, p13 = 0.f;
  float p20 = 0.f, p21 = 0.f, p22 = 0.f, p23 = 0.f;
  float p30 = 0.f, p31 = 0.f, p32 = 0.f, p33 = 0.f;

#define EPI_ONE(A, jj, r, P) { \
    const float tv = Tb[(size_t)(jbase + jj * 16 + q * 4 + r) * HH + h]; \
    const float hv = A[r] + pv + tv; \
    const float sv = hv * __frcp_rn(1.f + __expf(-hv)); \
    P = fmaf(sv, w2v, P); }

#define EPI_HH(hh, A0, A1, A2, A3) { \
    const int h = hg * 64 + hh * 16 + cc; \
    const float w2v = w2_s[h]; \
    const float pv  = pre_s[h]; \
    EPI_ONE(A0, 0, 0, p00) EPI_ONE(A0, 0, 1, p01) EPI_ONE(A0, 0, 2, p02) EPI_ONE(A0, 0, 3, p03) \
    EPI_ONE(A1, 1, 0, p10) EPI_ONE(A1, 1, 1, p11) EPI_ONE(A1, 1, 2, p12) EPI_ONE(A1, 1, 3, p13) \
    EPI_ONE(A2, 2, 0, p20) EPI_ONE(A2, 2, 1, p21) EPI_ONE(A2, 2, 2, p22) EPI_ONE(A2, 2, 3, p23) \
    EPI_ONE(A3, 3, 0, p30) EPI_ONE(A3, 3, 1, p31) EPI_ONE(A3, 3, 2, p32) EPI_ONE(A3, 3, 3, p33) }

  EPI_HH(0, a00, a10, a20, a30)
  EPI_HH(1, a01, a11, a21, a31)
  EPI_HH(2, a02, a12, a22, a32)
  EPI_HH(3, a03, a13, a23, a33)

#define REDW(P, jj, r) { \
    float v = P; \
    v += __shfl_xor(v, 1); v += __shfl_xor(v, 2); \
    v += __shfl_xor(v, 4); v += __shfl_xor(v, 8); \
    if (cc == 0) sc_s[hg][jj * 16 + q * 4 + r] = v; }

  REDW(p00, 0, 0) REDW(p01, 0, 1) REDW(p02, 0, 2) REDW(p03, 0, 3)
  REDW(p10, 1, 0) REDW(p11, 1, 1) REDW(p12, 1, 2) REDW(p13, 1, 3)
  REDW(p20, 2, 0) REDW(p21, 2, 1) REDW(p22, 2, 2) REDW(p23, 2, 3)
  REDW(p30, 3, 0) REDW(p31, 3, 1) REDW(p32, 3, 2) REDW(p33, 3, 3)
  __syncthreads();

  if (t < 64) {
    float s = sc_s[0][t] + sc_s[1][t] + sc_s[2][t] + sc_s[3][t] + b2[0];
    const int jg = jbase + t;
    if (jg == i) s = NEGV;
    Sc[(size_t)bi * NN + jg] = s;
  }
}

// ---------------- softmax over j, one block per (b,i) --------------------------
__global__ __launch_bounds__(256) void softmax_kernel(const float* __restrict__ Sc,
                                                      float* __restrict__ out) {
  const int bi = blockIdx.x;
  const int t  = threadIdx.x;
  __shared__ float red[NN];
  const float s = Sc[(size_t)bi * NN + t];
  red[t] = s;
  __syncthreads();
  for (int k = 128; k > 0; k >>= 1) {
    if (t < k) red[t] = fmaxf(red[t], red[t + k]);
    __syncthreads();
  }
  const float m = red[0];
  __syncthreads();
  const float e = __expf(s - m);
  red[t] = e;
  __syncthreads();
  for (int k = 128; k > 0; k >>= 1) {
    if (t < k) red[t] += red[t + k];
    __syncthreads();
  }
  out[(size_t)bi * NN + t] = e / red[0];
}

extern "C" void kernel_launch(void* const* d_in, const int* in_sizes, int n_in,
                              void* d_out, int out_size, void* d_ws, size_t ws_size,
                              hipStream_t stream) {
  const float* X  = (const float*)d_in[0];
  const float* W1 = (const float*)d_in[1];
  const float* b1 = (const float*)d_in[2];
  const float* W2 = (const float*)d_in[3];
  const float* b2 = (const float*)d_in[4];
  float* out = (float*)d_out;

  float*     Sws = (float*)d_ws;                             // 1 MB
  float*     Tws = Sws + (size_t)BB * NN * HH;               // 1 MB
  _Float16*  Wst = (_Float16*)(Tws + (size_t)BB * NN * HH);  // 256 KB
  _Float16*  Xhw = Wst + (size_t)16 * HH * 32;               // 512 KB
  float*     Scw = (float*)(Xhw + (size_t)BB * 64 * 256 * 4);// 1 MB

  prep_kernel<<<256, 256, 0, stream>>>(X, W1, Sws, Tws, Wst, Xhw);
  score_mfma<<<BB * NN * 4, 256, 0, stream>>>(X, b1, W2, b2, Sws, Tws, Wst, Xhw, Scw);
  softmax_kernel<<<BB * NN, 256, 0, stream>>>(Scw, out);
}

// Round 15
// 204.324 us; speedup vs baseline: 1.3537x; 1.3537x over previous
//
#include <hip/hip_runtime.h>

#define BB 4
#define NN 256
#define DD 256
#define HH 256
#define NEGV -1.0e9f

typedef _Float16 half8 __attribute__((ext_vector_type(8)));
typedef __fp16   fp16x2 __attribute__((ext_vector_type(2)));
typedef float floatx4 __attribute__((ext_vector_type(4)));

// ---------------- prep: Wc/Wd -> f16 fragment-contiguous; S/T ------------------
// Wst layout: [ks 0..15][hgrp 0..15][q 0..3][cc 0..15][e 0..7] halves.
// Fragment (ks,hgrp,q) holds B16[k=ks*32+q*8+e][h=hgrp*16+cc]; k=2*d+t
// (t=0: Wc[d][h], t=1: Wd[d][h]).  (R13's verified-correct map.)
__global__ __launch_bounds__(256) void prep_kernel(const float* __restrict__ X,
                                                   const float* __restrict__ W1,
                                                   float* __restrict__ S,
                                                   float* __restrict__ T,
                                                   _Float16* __restrict__ Wst) {
  const int g = blockIdx.x;    // d = 0..255
  const int h = threadIdx.x;   // 0..255

  {
    const float wcv = W1[(size_t)(2 * DD + g) * HH + h];
    const float wdv = W1[(size_t)(3 * DD + g) * HH + h];
    const int ks = g >> 4;
    const int dd = g & 15;
    const int q  = dd >> 2;
    const int e  = (dd & 3) * 2;
    const int hgrp = h >> 4;
    const int ccw  = h & 15;
    _Float16* p = Wst + ((size_t)((ks * 16 + hgrp) * 4 + q) * 16 + ccw) * 8 + e;
    p[0] = (_Float16)wcv;
    p[1] = (_Float16)wdv;
  }

  const int row0 = g * 4;
  __shared__ float xr[4][DD];
#pragma unroll
  for (int r = 0; r < 4; ++r) xr[r][h] = X[(size_t)(row0 + r) * DD + h];
  __syncthreads();

  const float* __restrict__ Wa = W1;
  const float* __restrict__ Wb = W1 + (size_t)DD * HH;
  float sa0 = 0.f, sa1 = 0.f, sa2 = 0.f, sa3 = 0.f;
  float sb0 = 0.f, sb1 = 0.f, sb2 = 0.f, sb3 = 0.f;
#pragma unroll 4
  for (int d = 0; d < DD; ++d) {
    const float wa = Wa[(size_t)d * HH + h];
    const float wb = Wb[(size_t)d * HH + h];
    sa0 = fmaf(xr[0][d], wa, sa0);  sb0 = fmaf(xr[0][d], wb, sb0);
    sa1 = fmaf(xr[1][d], wa, sa1);  sb1 = fmaf(xr[1][d], wb, sb1);
    sa2 = fmaf(xr[2][d], wa, sa2);  sb2 = fmaf(xr[2][d], wb, sb2);
    sa3 = fmaf(xr[3][d], wa, sa3);  sb3 = fmaf(xr[3][d], wb, sb3);
  }
  S[(size_t)(row0 + 0) * HH + h] = sa0;  T[(size_t)(row0 + 0) * HH + h] = sb0;
  S[(size_t)(row0 + 1) * HH + h] = sa1;  T[(size_t)(row0 + 1) * HH + h] = sb1;
  S[(size_t)(row0 + 2) * HH + h] = sa2;  T[(size_t)(row0 + 2) * HH + h] = sb2;
  S[(size_t)(row0 + 3) * HH + h] = sa3;  T[(size_t)(row0 + 3) * HH + h] = sb3;
}

__device__ __forceinline__ half8 make_afrag(const float4 xi, const float4 xj) {
  fp16x2 p0 = __builtin_amdgcn_cvt_pkrtz(__builtin_fabsf(xi.x - xj.x), xi.x * xj.x);
  fp16x2 p1 = __builtin_amdgcn_cvt_pkrtz(__builtin_fabsf(xi.y - xj.y), xi.y * xj.y);
  fp16x2 p2 = __builtin_amdgcn_cvt_pkrtz(__builtin_fabsf(xi.z - xj.z), xi.z * xj.z);
  fp16x2 p3 = __builtin_amdgcn_cvt_pkrtz(__builtin_fabsf(xi.w - xj.w), xi.w * xj.w);
  uint4 u;
  u.x = __builtin_bit_cast(unsigned int, p0);
  u.y = __builtin_bit_cast(unsigned int, p1);
  u.z = __builtin_bit_cast(unsigned int, p2);
  u.w = __builtin_bit_cast(unsigned int, p3);
  return __builtin_bit_cast(half8, u);
}

#define MFMA16(af, bf, acc) acc = __builtin_amdgcn_mfma_f32_16x16x32_f16(af, bf, acc, 0, 0, 0)

// ---------------- score: one block per (b,i) x 64-j quarter --------------------
// R13's MfmaUtil(20.6%)x147us = 30us == the MFMA floor: the pipe starves 80% of
// the time on the per-kstep load->afrag->MFMA chain, replicated in all hg-waves.
// FIX: Phase 1 builds ALL A-fragments (16 ksteps x 64 j, 64 KB) into LDS once
// (one barrier); Phase 2's K-loop is only 4 ds_read_b128 + 4 global_b128 + 16
// MFMA per kstep — no A-gen VALU, no barriers, 4x A-reuse across hg-waves.
// LDS ~69 KB -> 2 blocks/CU; __launch_bounds__(256,2) -> 256-reg cap, no spill.
__global__ __launch_bounds__(256, 2) void score_mfma(
    const float* __restrict__ X,  const float* __restrict__ b1,
    const float* __restrict__ W2, const float* __restrict__ b2,
    const float* __restrict__ S,  const float* __restrict__ T,
    const _Float16* __restrict__ Wst, float* __restrict__ Sc) {

  const int blk   = blockIdx.x;
  const int bi    = blk >> 2;       // b*256 + i
  const int jbase = (blk & 3) * 64;
  const int b     = bi >> 8;
  const int i     = bi & 255;
  const int t     = threadIdx.x;
  const int lane  = t & 63;
  const int hg    = t >> 6;         // 0..3
  const int q     = lane >> 4;
  const int cc    = lane & 15;

  __shared__ __align__(16) float    xi_s[DD];
  __shared__ __align__(16) _Float16 Af[32768];   // 64 KB: [ks][jg][q][cc][e]
  __shared__ float pre_s[HH];
  __shared__ float w2_s[HH];
  __shared__ float sc_s[4][64];

  xi_s[t]  = X[(size_t)bi * DD + t];
  pre_s[t] = S[(size_t)bi * HH + t] + b1[t];
  w2_s[t]  = W2[t];
  __syncthreads();

  const float* __restrict__ Tb = T + (size_t)b * NN * HH;

  // ---- Phase 1: build all A-fragments into LDS (once per block) ----
  // Thread t: j = jbase + (t&63); covers ksq = (t>>6)*16 + idx, idx 0..15.
  // ksq = ks*4+q -> d0 = ksq*4; frag halves at (ks*16 + jg*4 + q)*128 + cc*8.
  {
    const int jloc = t & 63;
    const int jg   = jloc >> 4;
    const int ccw  = jloc & 15;
    const float* __restrict__ xjrow = X + (size_t)(b * NN + jbase + jloc) * DD;
#pragma unroll
    for (int idx = 0; idx < 16; ++idx) {
      const int ksq = (t >> 6) * 16 + idx;   // 0..63
      const int d0  = ksq * 4;
      const int ks  = ksq >> 2;
      const int qw  = ksq & 3;
      const float4 xi4 = *(const float4*)&xi_s[d0];
      const float4 xj4 = *(const float4*)(xjrow + d0);
      *(half8*)&Af[(ks * 16 + jg * 4 + qw) * 128 + ccw * 8] = make_afrag(xi4, xj4);
    }
  }
  __syncthreads();                    // Af ready; no more barriers until epilogue

  // B source: byte addr Wst + ks*16384 + hg*4096 + lane*16 (+1024 per hh)
  const char* __restrict__ bsrc = (const char*)Wst + hg * 4096 + (size_t)lane * 16;

  floatx4 a00 = (floatx4)0.f, a01 = (floatx4)0.f, a02 = (floatx4)0.f, a03 = (floatx4)0.f;
  floatx4 a10 = (floatx4)0.f, a11 = (floatx4)0.f, a12 = (floatx4)0.f, a13 = (floatx4)0.f;
  floatx4 a20 = (floatx4)0.f, a21 = (floatx4)0.f, a22 = (floatx4)0.f, a23 = (floatx4)0.f;
  floatx4 a30 = (floatx4)0.f, a31 = (floatx4)0.f, a32 = (floatx4)0.f, a33 = (floatx4)0.f;

#pragma unroll 2
  for (int ks = 0; ks < 16; ++ks) {
    const char* bk = bsrc + ks * 16384;
    const half8 bf0 = *(const half8*)(bk);
    const half8 bf1 = *(const half8*)(bk + 1024);
    const half8 bf2 = *(const half8*)(bk + 2048);
    const half8 bf3 = *(const half8*)(bk + 3072);
    const _Float16* __restrict__ ap = &Af[ks * 2048 + lane * 8];
    {
      const half8 af = *(const half8*)(ap);          // jg 0
      MFMA16(af, bf0, a00); MFMA16(af, bf1, a01); MFMA16(af, bf2, a02); MFMA16(af, bf3, a03);
    }
    {
      const half8 af = *(const half8*)(ap + 512);    // jg 1
      MFMA16(af, bf0, a10); MFMA16(af, bf1, a11); MFMA16(af, bf2, a12); MFMA16(af, bf3, a13);
    }
    {
      const half8 af = *(const half8*)(ap + 1024);   // jg 2
      MFMA16(af, bf0, a20); MFMA16(af, bf1, a21); MFMA16(af, bf2, a22); MFMA16(af, bf3, a23);
    }
    {
      const half8 af = *(const half8*)(ap + 1536);   // jg 3
      MFMA16(af, bf0, a30); MFMA16(af, bf1, a31); MFMA16(af, bf2, a32); MFMA16(af, bf3, a33);
    }
  }

  // ---- epilogue: + S_i + T_j + b1, silu, dot w2 ----
  float p00 = 0.f, p01 = 0.f, p02 = 0.f, p03 = 0.f;
  float p10 = 0.f, p11 = 0.f, p12 = 0.f, p13 = 0.f;
  float p20 = 0.f, p21 = 0.f, p22 = 0.f, p23 = 0.f;
  float p30 = 0.f, p31 = 0.f, p32 = 0.f, p33 = 0.f;

#define EPI_ONE(A, jj, r, P) { \
    const float tv = Tb[(size_t)(jbase + jj * 16 + q * 4 + r) * HH + h]; \
    const float hv = A[r] + pv + tv; \
    const float sv = hv * __frcp_rn(1.f + __expf(-hv)); \
    P = fmaf(sv, w2v, P); }

#define EPI_HH(hh, A0, A1, A2, A3) { \
    const int h = hg * 64 + hh * 16 + cc; \
    const float w2v = w2_s[h]; \
    const float pv  = pre_s[h]; \
    EPI_ONE(A0, 0, 0, p00) EPI_ONE(A0, 0, 1, p01) EPI_ONE(A0, 0, 2, p02) EPI_ONE(A0, 0, 3, p03) \
    EPI_ONE(A1, 1, 0, p10) EPI_ONE(A1, 1, 1, p11) EPI_ONE(A1, 1, 2, p12) EPI_ONE(A1, 1, 3, p13) \
    EPI_ONE(A2, 2, 0, p20) EPI_ONE(A2, 2, 1, p21) EPI_ONE(A2, 2, 2, p22) EPI_ONE(A2, 2, 3, p23) \
    EPI_ONE(A3, 3, 0, p30) EPI_ONE(A3, 3, 1, p31) EPI_ONE(A3, 3, 2, p32) EPI_ONE(A3, 3, 3, p33) }

  EPI_HH(0, a00, a10, a20, a30)
  EPI_HH(1, a01, a11, a21, a31)
  EPI_HH(2, a02, a12, a22, a32)
  EPI_HH(3, a03, a13, a23, a33)

#define REDW(P, jj, r) { \
    float v = P; \
    v += __shfl_xor(v, 1); v += __shfl_xor(v, 2); \
    v += __shfl_xor(v, 4); v += __shfl_xor(v, 8); \
    if (cc == 0) sc_s[hg][jj * 16 + q * 4 + r] = v; }

  REDW(p00, 0, 0) REDW(p01, 0, 1) REDW(p02, 0, 2) REDW(p03, 0, 3)
  REDW(p10, 1, 0) REDW(p11, 1, 1) REDW(p12, 1, 2) REDW(p13, 1, 3)
  REDW(p20, 2, 0) REDW(p21, 2, 1) REDW(p22, 2, 2) REDW(p23, 2, 3)
  REDW(p30, 3, 0) REDW(p31, 3, 1) REDW(p32, 3, 2) REDW(p33, 3, 3)
  __syncthreads();

  if (t < 64) {
    float s = sc_s[0][t] + sc_s[1][t] + sc_s[2][t] + sc_s[3][t] + b2[0];
    const int jg = jbase + t;
    if (jg == i) s = NEGV;
    Sc[(size_t)bi * NN + jg] = s;
  }
}

// ---------------- softmax over j, one block per (b,i) --------------------------
__global__ __launch_bounds__(256) void softmax_kernel(const float* __restrict__ Sc,
                                                      float* __restrict__ out) {
  const int bi = blockIdx.x;
  const int t  = threadIdx.x;
  __shared__ float red[NN];
  const float s = Sc[(size_t)bi * NN + t];
  red[t] = s;
  __syncthreads();
  for (int k = 128; k > 0; k >>= 1) {
    if (t < k) red[t] = fmaxf(red[t], red[t + k]);
    __syncthreads();
  }
  const float m = red[0];
  __syncthreads();
  const float e = __expf(s - m);
  red[t] = e;
  __syncthreads();
  for (int k = 128; k > 0; k >>= 1) {
    if (t < k) red[t] += red[t + k];
    __syncthreads();
  }
  out[(size_t)bi * NN + t] = e / red[0];
}

extern "C" void kernel_launch(void* const* d_in, const int* in_sizes, int n_in,
                              void* d_out, int out_size, void* d_ws, size_t ws_size,
                              hipStream_t stream) {
  const float* X  = (const float*)d_in[0];
  const float* W1 = (const float*)d_in[1];
  const float* b1 = (const float*)d_in[2];
  const float* W2 = (const float*)d_in[3];
  const float* b2 = (const float*)d_in[4];
  float* out = (float*)d_out;

  float*     Sws = (float*)d_ws;                             // 1 MB
  float*     Tws = Sws + (size_t)BB * NN * HH;               // 1 MB
  _Float16*  Wst = (_Float16*)(Tws + (size_t)BB * NN * HH);  // 256 KB
  float*     Scw = (float*)(Wst + (size_t)16 * HH * 32);     // 1 MB

  prep_kernel<<<256, 256, 0, stream>>>(X, W1, Sws, Tws, Wst);
  score_mfma<<<BB * NN * 4, 256, 0, stream>>>(X, b1, W2, b2, Sws, Tws, Wst, Scw);
  softmax_kernel<<<BB * NN, 256, 0, stream>>>(Scw, out);
}